// Round 1
// baseline (476.731 us; speedup 1.0000x reference)
//
#include <hip/hip_runtime.h>

// Fused 1x1-conv GEMM + GroupNorm + HardTanh, MI355X (gfx950).
// Round 1: pre-transpose x to [B][HW][Cin] f16, then two MFMA GEMM passes
// (pass 1: stats only; pass 2: normalize+clamp+store). See journal for roofline.

#define HW    3136
#define CIN   256
#define COUT  512
#define BATCH 32
#define NG    32
#define CPG   16
#define EPS   1e-5f
#define HT_MIN -2.0f
#define HT_MAX  2.0f

typedef _Float16 f16x8 __attribute__((ext_vector_type(8)));
typedef float    f32x4 __attribute__((ext_vector_type(4)));

// ---------------------------------------------------------------------------
// K0: x [B][CIN][HW] fp32  ->  xT [B][HW][CIN] f16 (64x64 LDS tile transpose)
//     + convert w -> f16, + zero the stats accumulator (ws is poisoned 0xAA).
// ---------------------------------------------------------------------------
__global__ __launch_bounds__(256) void k0_transpose(
    const float* __restrict__ x, const float* __restrict__ w,
    _Float16* __restrict__ xT, _Float16* __restrict__ wf,
    float* __restrict__ stats)
{
  __shared__ __align__(16) _Float16 T[64 * 72];   // +8 pad breaks write conflicts
  const int bid = blockIdx.x;
  const int t   = threadIdx.x;
  const int b   = bid / 196;       // 49 s-tiles * 4 c-tiles
  const int r   = bid % 196;
  const int st  = r >> 2;          // 0..48
  const int ct  = r & 3;           // 0..3
  const int s0  = st * 64, c0 = ct * 64;

  const float* xb = x + ((size_t)b * CIN + c0) * HW + s0;
  {
    const int s_loc = t & 63;
    const int cbase = t >> 6;
#pragma unroll
    for (int rr = 0; rr < 16; ++rr) {
      const int c_loc = cbase + rr * 4;                 // coalesced 256B reads
      T[s_loc * 72 + c_loc] = (_Float16)xb[(size_t)c_loc * HW + s_loc];
    }
  }
  __syncthreads();
  {
    const int s_loc = t >> 2;
    const int cg    = (t & 3) * 16;                     // 32B per thread
    const uint4 v0 = *(const uint4*)(T + s_loc * 72 + cg);
    const uint4 v1 = *(const uint4*)(T + s_loc * 72 + cg + 8);
    _Float16* dst = xT + ((size_t)b * HW + s0 + s_loc) * CIN + c0 + cg;
    *(uint4*)(dst)     = v0;
    *(uint4*)(dst + 8) = v1;
  }
  if (bid < (COUT * CIN) / 256) wf[bid * 256 + t] = (_Float16)w[bid * 256 + t];
  if (bid < 8)                  stats[bid * 256 + t] = 0.f;
}

// ---------------------------------------------------------------------------
// GEMM: C[128co x 128s] per block, BK=64, 4 waves (2x2), 4x4 16x16x32 f16 MFMA
// tiles per wave. LDS: [row][8 chunks of 16B], chunk XOR-swizzled by (row&7)
// -> conflict-free ds_read_b128 / ds_write_b128, no padding.
// WRITE_OUT=0: accumulate group sums (sum, sumsq) via wave-reduce + atomics.
// WRITE_OUT=1: normalize with mean/rsig, gamma/beta, clamp, store fp32.
// Zero-filled OOB spatial columns contribute exactly 0 to stats.
// ---------------------------------------------------------------------------
template<int WRITE_OUT>
__global__ __launch_bounds__(256) void k_gemm(
    const _Float16* __restrict__ xT, const _Float16* __restrict__ wf,
    float* __restrict__ stats, const float* __restrict__ mr,
    const float* __restrict__ gamma, const float* __restrict__ beta,
    float* __restrict__ out)
{
  __shared__ __align__(16) _Float16 As[128 * 64];
  __shared__ __align__(16) _Float16 Bs[128 * 64];

  const int bid = blockIdx.x;
  const int b   = bid / 100;       // 4 mt * 25 nt; mt fastest for x-tile L2 reuse
  const int r   = bid % 100;
  const int mt  = r & 3;
  const int nt  = r >> 2;
  const int s0  = nt * 128;

  const int t    = threadIdx.x;
  const int lane = t & 63;
  const int wid  = t >> 6;
  const int wy   = wid >> 1, wx = wid & 1;

  f32x4 acc[4][4] = {};

  const _Float16* xb = xT + (size_t)b * HW * CIN;

  for (int kt = 0; kt < CIN / 64; ++kt) {
    __syncthreads();
    // stage A (weights): 128 rows x 64 k
#pragma unroll
    for (int u = 0; u < 4; ++u) {
      const int flat = t + u * 256;          // 0..1023 16B-chunks
      const int m  = flat >> 3;
      const int cc = flat & 7;
      const uint4 v = *(const uint4*)(wf + ((mt * 128 + m) * CIN + kt * 64 + cc * 8));
      *(uint4*)(As + m * 64 + ((cc ^ (m & 7)) * 8)) = v;
    }
    // stage B (xT): 128 spatial x 64 k, zero-fill s >= HW
#pragma unroll
    for (int u = 0; u < 4; ++u) {
      const int flat = t + u * 256;
      const int n  = flat >> 3;
      const int cc = flat & 7;
      const int s  = s0 + n;
      uint4 v = make_uint4(0u, 0u, 0u, 0u);
      if (s < HW) v = *(const uint4*)(xb + ((size_t)s * CIN + kt * 64 + cc * 8));
      *(uint4*)(Bs + n * 64 + ((cc ^ (n & 7)) * 8)) = v;
    }
    __syncthreads();
#pragma unroll
    for (int ks = 0; ks < 2; ++ks) {
      const int q = lane >> 4;
      const int c = ks * 4 + q;              // chunk holding k = ks*32 + q*8 ..
      f16x8 af[4], bfr[4];
#pragma unroll
      for (int mi = 0; mi < 4; ++mi) {
        const int m = wy * 64 + mi * 16 + (lane & 15);
        af[mi] = *(const f16x8*)(As + m * 64 + ((c ^ (m & 7)) * 8));
      }
#pragma unroll
      for (int ni = 0; ni < 4; ++ni) {
        const int n = wx * 64 + ni * 16 + (lane & 15);
        bfr[ni] = *(const f16x8*)(Bs + n * 64 + ((c ^ (n & 7)) * 8));
      }
#pragma unroll
      for (int mi = 0; mi < 4; ++mi)
#pragma unroll
        for (int ni = 0; ni < 4; ++ni)
          acc[mi][ni] = __builtin_amdgcn_mfma_f32_16x16x32_f16(
              af[mi], bfr[ni], acc[mi][ni], 0, 0, 0);
    }
  }

  if (WRITE_OUT == 0) {
    // each 16-row MFMA m-tile is exactly one GroupNorm group
#pragma unroll
    for (int mi = 0; mi < 4; ++mi) {
      float s1 = 0.f, s2 = 0.f;
#pragma unroll
      for (int ni = 0; ni < 4; ++ni)
#pragma unroll
        for (int rr = 0; rr < 4; ++rr) {
          const float v = acc[mi][ni][rr];
          s1 += v; s2 += v * v;
        }
#pragma unroll
      for (int off = 32; off > 0; off >>= 1) {
        s1 += __shfl_down(s1, off, 64);
        s2 += __shfl_down(s2, off, 64);
      }
      if (lane == 0) {
        const int g = mt * 8 + wy * 4 + mi;
        atomicAdd(&stats[(b * NG + g) * 2 + 0], s1);
        atomicAdd(&stats[(b * NG + g) * 2 + 1], s2);
      }
    }
  } else {
#pragma unroll
    for (int mi = 0; mi < 4; ++mi) {
      const int g = mt * 8 + wy * 4 + mi;
      const float mean = mr[(b * NG + g) * 2 + 0];
      const float rsig = mr[(b * NG + g) * 2 + 1];
      const int row0 = mt * 128 + wy * 64 + mi * 16 + ((lane >> 4) << 2);
#pragma unroll
      for (int rr = 0; rr < 4; ++rr) {
        const int co = row0 + rr;
        const float sc = rsig * gamma[co];
        const float sh = beta[co] - mean * sc;
        float* orow = out + ((size_t)b * COUT + co) * HW;
#pragma unroll
        for (int ni = 0; ni < 4; ++ni) {
          const int s = s0 + wx * 64 + ni * 16 + (lane & 15);
          if (s < HW) {
            float v = acc[mi][ni][rr] * sc + sh;
            v = fminf(fmaxf(v, HT_MIN), HT_MAX);
            orow[s] = v;
          }
        }
      }
    }
  }
}

// ---------------------------------------------------------------------------
// K2: finalize mean / rsqrt(var+eps) for the 1024 (b, group) pairs
// ---------------------------------------------------------------------------
__global__ void k_finalize(const float* __restrict__ stats, float* __restrict__ mr)
{
  const int i = blockIdx.x * 256 + threadIdx.x;
  if (i < BATCH * NG) {
    const float cnt  = (float)(CPG * HW);
    const float mean = stats[i * 2] / cnt;
    const float var  = stats[i * 2 + 1] / cnt - mean * mean;
    mr[i * 2]     = mean;
    mr[i * 2 + 1] = rsqrtf(var + EPS);
  }
}

extern "C" void kernel_launch(void* const* d_in, const int* in_sizes, int n_in,
                              void* d_out, int out_size, void* d_ws, size_t ws_size,
                              hipStream_t stream)
{
  const float* x     = (const float*)d_in[0];
  const float* w     = (const float*)d_in[1];
  const float* gamma = (const float*)d_in[2];
  const float* beta  = (const float*)d_in[3];
  float* out = (float*)d_out;

  const size_t xT_bytes = (size_t)BATCH * HW * CIN * 2;  // 51,380,224
  const size_t wf_bytes = (size_t)COUT * CIN * 2;        //    262,144
  char* ws = (char*)d_ws;
  _Float16* xT = (_Float16*)ws;
  _Float16* wf = (_Float16*)(ws + xT_bytes);
  float* stats = (float*)(ws + xT_bytes + wf_bytes);     // 1024*2 f32
  float* mr    = (float*)(ws + xT_bytes + wf_bytes + 8192);

  if (ws_size < xT_bytes + wf_bytes + 16384) return;     // scratch too small

  k0_transpose<<<dim3(BATCH * 196), dim3(256), 0, stream>>>(x, w, xT, wf, stats);
  k_gemm<0><<<dim3(BATCH * 100), dim3(256), 0, stream>>>(
      xT, wf, stats, nullptr, nullptr, nullptr, nullptr);
  k_finalize<<<dim3(4), dim3(256), 0, stream>>>(stats, mr);
  k_gemm<1><<<dim3(BATCH * 100), dim3(256), 0, stream>>>(
      xT, wf, nullptr, mr, gamma, beta, out);
}

// Round 2
// 402.311 us; speedup vs baseline: 1.1850x; 1.1850x over previous
//
#include <hip/hip_runtime.h>

// Fused 1x1-conv GEMM + GroupNorm + HardTanh, MI355X (gfx950).
// Round 2: global_load_lds(16B) staging w/ global-side XOR permutation,
// XCD-aware block swizzle for B-tile L2 reuse, edge-tile overlap (no OOB
// guards), conflict-free k0 transpose (fp32 LDS, stride-65 rows).

#define HW    3136
#define CIN   256
#define COUT  512
#define BATCH 32
#define NG    32
#define CPG   16
#define EPS   1e-5f

typedef _Float16 f16x8 __attribute__((ext_vector_type(8)));
typedef float    f32x4 __attribute__((ext_vector_type(4)));
typedef unsigned int u32;

// async global->LDS DMA, 16B per lane; LDS dest = wave-uniform base + lane*16
__device__ __forceinline__ void gload16(const void* g, void* l) {
  __builtin_amdgcn_global_load_lds(
      (const u32 __attribute__((address_space(1)))*)g,
      (u32 __attribute__((address_space(3)))*)l, 16, 0, 0);
}

// ---------------------------------------------------------------------------
// K0: x [B][CIN][HW] f32 -> xT [B][HW][CIN] f16. 64x64 tile via fp32 LDS,
// row stride 65 dwords => <=2-way bank aliasing on both phases (free).
// Also converts w->f16 and zeroes the stats accumulator.
// ---------------------------------------------------------------------------
__global__ __launch_bounds__(256) void k0_transpose(
    const float* __restrict__ x, const float* __restrict__ w,
    _Float16* __restrict__ xT, _Float16* __restrict__ wf,
    float* __restrict__ stats)
{
  __shared__ float T[64 * 65];
  const int bid = blockIdx.x;
  const int t   = threadIdx.x;
  const int b   = bid / 196;       // 49 s-tiles * 4 c-tiles
  const int r   = bid % 196;
  const int st  = r >> 2;
  const int ct  = r & 3;
  const int s0  = st * 64, c0 = ct * 64;

  const float* xb = x + ((size_t)b * CIN + c0) * HW + s0;
  // phase 1: float4 reads along s (coalesced), scalar LDS writes
#pragma unroll
  for (int rr = 0; rr < 4; ++rr) {
    const int c_loc = (t >> 4) + rr * 16;
    const int s4    = (t & 15) * 4;
    const float4 v  = *(const float4*)(xb + (size_t)c_loc * HW + s4);
    T[(s4 + 0) * 65 + c_loc] = v.x;
    T[(s4 + 1) * 65 + c_loc] = v.y;
    T[(s4 + 2) * 65 + c_loc] = v.z;
    T[(s4 + 3) * 65 + c_loc] = v.w;
  }
  __syncthreads();
  // phase 2: 8 scalar LDS reads -> f16x8 -> 16B coalesced global store
#pragma unroll
  for (int p = 0; p < 2; ++p) {
    const int s_loc = p * 32 + (t >> 3);
    const int cg    = (t & 7) * 8;
    f16x8 o;
#pragma unroll
    for (int j = 0; j < 8; ++j) o[j] = (_Float16)T[s_loc * 65 + cg + j];
    *(f16x8*)(xT + ((size_t)b * HW + s0 + s_loc) * CIN + c0 + cg) = o;
  }
  if (bid < (COUT * CIN) / 256) wf[bid * 256 + t] = (_Float16)w[bid * 256 + t];
  if (bid < 8)                  stats[bid * 256 + t] = 0.f;
}

// ---------------------------------------------------------------------------
// GEMM: C[128co x 128s] per block, BK=64, 4 waves (2x2), 4x4 16x16x32 f16
// MFMA tiles/wave. Staging via global_load_lds: lane l of a wave lands at
// LDS chunk l; we permute the GLOBAL chunk index ((l&7)^(l>>3)) so the LDS
// image carries the XOR swizzle -> conflict-free ds_read_b128 on read side.
// Edge tile nt==24 overlaps (s0=3008): stores are idempotent recompute;
// stats predicate to s>=3072 to avoid double counting.
// WRITE_OUT=0: group sums via wave-reduce + atomics (group = 16-row m-tile).
// WRITE_OUT=1: normalize, gamma/beta, clamp [-2,2], fp32 store.
// ---------------------------------------------------------------------------
template<int WRITE_OUT>
__global__ __launch_bounds__(256) void k_gemm(
    const _Float16* __restrict__ xT, const _Float16* __restrict__ wf,
    float* __restrict__ stats, const float* __restrict__ mr,
    const float* __restrict__ gamma, const float* __restrict__ beta,
    float* __restrict__ out)
{
  __shared__ __align__(16) _Float16 As[128 * 64];
  __shared__ __align__(16) _Float16 Bs[128 * 64];

  // XCD swizzle: 3200 blocks = 8 XCDs x 400 slots; mt fastest within an XCD
  // so the 4 mt-siblings sharing a B-tile hit the same XCD's L2.
  const int bid  = blockIdx.x;
  const int tile = (bid & 7) * 400 + (bid >> 3);
  const int mt   = tile & 3;
  const int q2   = tile >> 2;
  const int nt   = q2 % 25;
  const int b    = q2 / 25;
  const int s0   = (nt == 24) ? (HW - 128) : nt * 128;

  const int t    = threadIdx.x;
  const int lane = t & 63;
  const int wid  = t >> 6;
  const int wy   = wid >> 1, wx = wid & 1;
  const int lr   = lane >> 3;          // LDS row-within-8 this lane fills
  const int ccg  = (lane & 7) ^ lr;    // global-side chunk permutation

  f32x4 acc[4][4] = {};
  const _Float16* xb = xT + (size_t)b * HW * CIN;

  for (int kt = 0; kt < 4; ++kt) {
    __syncthreads();                   // prior-iter readers done
    const int ko = kt * 64;
#pragma unroll
    for (int u = 0; u < 4; ++u) {
      const int rowb = (wid * 4 + u) * 8 + lr;           // 0..127 across waves
      gload16(wf + (size_t)(mt * 128 + rowb) * CIN + ko + ccg * 8,
              As + (wid * 4 + u) * 512);
      gload16(xb + (size_t)(s0 + rowb) * CIN + ko + ccg * 8,
              Bs + (wid * 4 + u) * 512);
    }
    __syncthreads();                   // vmcnt drain + barrier -> data visible
#pragma unroll
    for (int ks = 0; ks < 2; ++ks) {
      const int c = ks * 4 + (lane >> 4);
      f16x8 af[4], bfr[4];
#pragma unroll
      for (int mi = 0; mi < 4; ++mi) {
        const int m = wy * 64 + mi * 16 + (lane & 15);
        af[mi] = *(const f16x8*)(As + m * 64 + ((c ^ (m & 7)) * 8));
      }
#pragma unroll
      for (int ni = 0; ni < 4; ++ni) {
        const int n = wx * 64 + ni * 16 + (lane & 15);
        bfr[ni] = *(const f16x8*)(Bs + n * 64 + ((c ^ (n & 7)) * 8));
      }
#pragma unroll
      for (int mi = 0; mi < 4; ++mi)
#pragma unroll
        for (int ni = 0; ni < 4; ++ni)
          acc[mi][ni] = __builtin_amdgcn_mfma_f32_16x16x32_f16(
              af[mi], bfr[ni], acc[mi][ni], 0, 0, 0);
    }
  }

  if (WRITE_OUT == 0) {
    const int slo  = (nt == 24) ? 3072 : 0;   // skip cols already counted
    const int colb = s0 + wx * 64 + (lane & 15);
#pragma unroll
    for (int mi = 0; mi < 4; ++mi) {
      float s1 = 0.f, s2 = 0.f;
#pragma unroll
      for (int ni = 0; ni < 4; ++ni) {
        if (colb + ni * 16 >= slo) {
#pragma unroll
          for (int rr = 0; rr < 4; ++rr) {
            const float v = acc[mi][ni][rr];
            s1 += v; s2 += v * v;
          }
        }
      }
#pragma unroll
      for (int off = 32; off > 0; off >>= 1) {
        s1 += __shfl_down(s1, off, 64);
        s2 += __shfl_down(s2, off, 64);
      }
      if (lane == 0) {
        const int g = mt * 8 + wy * 4 + mi;
        atomicAdd(&stats[(b * NG + g) * 2 + 0], s1);
        atomicAdd(&stats[(b * NG + g) * 2 + 1], s2);
      }
    }
  } else {
#pragma unroll
    for (int mi = 0; mi < 4; ++mi) {
      const int g = mt * 8 + wy * 4 + mi;
      const float mean = mr[(b * NG + g) * 2 + 0];
      const float rsig = mr[(b * NG + g) * 2 + 1];
      const int row0 = mt * 128 + wy * 64 + mi * 16 + ((lane >> 4) << 2);
#pragma unroll
      for (int rr = 0; rr < 4; ++rr) {
        const int co = row0 + rr;
        const float sc = rsig * gamma[co];
        const float sh = beta[co] - mean * sc;
        float* orow = out + ((size_t)b * COUT + co) * HW + s0 + wx * 64 + (lane & 15);
#pragma unroll
        for (int ni = 0; ni < 4; ++ni) {
          float v = acc[mi][ni][rr] * sc + sh;
          v = fminf(fmaxf(v, -2.0f), 2.0f);
          orow[ni * 16] = v;
        }
      }
    }
  }
}

// ---------------------------------------------------------------------------
// K2: finalize mean / rsqrt(var+eps) for the 1024 (b, group) pairs
// ---------------------------------------------------------------------------
__global__ void k_finalize(const float* __restrict__ stats, float* __restrict__ mr)
{
  const int i = blockIdx.x * 256 + threadIdx.x;
  if (i < BATCH * NG) {
    const float cnt  = (float)(CPG * HW);
    const float mean = stats[i * 2] / cnt;
    const float var  = stats[i * 2 + 1] / cnt - mean * mean;
    mr[i * 2]     = mean;
    mr[i * 2 + 1] = rsqrtf(var + EPS);
  }
}

extern "C" void kernel_launch(void* const* d_in, const int* in_sizes, int n_in,
                              void* d_out, int out_size, void* d_ws, size_t ws_size,
                              hipStream_t stream)
{
  const float* x     = (const float*)d_in[0];
  const float* w     = (const float*)d_in[1];
  const float* gamma = (const float*)d_in[2];
  const float* beta  = (const float*)d_in[3];
  float* out = (float*)d_out;

  const size_t xT_bytes = (size_t)BATCH * HW * CIN * 2;  // 51,380,224
  const size_t wf_bytes = (size_t)COUT * CIN * 2;        //    262,144
  char* ws = (char*)d_ws;
  _Float16* xT = (_Float16*)ws;
  _Float16* wf = (_Float16*)(ws + xT_bytes);
  float* stats = (float*)(ws + xT_bytes + wf_bytes);     // 1024*2 f32
  float* mr    = (float*)(ws + xT_bytes + wf_bytes + 8192);

  if (ws_size < xT_bytes + wf_bytes + 16384) return;     // scratch too small

  k0_transpose<<<dim3(BATCH * 196), dim3(256), 0, stream>>>(x, w, xT, wf, stats);
  k_gemm<0><<<dim3(BATCH * 100), dim3(256), 0, stream>>>(
      xT, wf, stats, nullptr, nullptr, nullptr, nullptr);
  k_finalize<<<dim3(4), dim3(256), 0, stream>>>(stats, mr);
  k_gemm<1><<<dim3(BATCH * 100), dim3(256), 0, stream>>>(
      xT, wf, nullptr, mr, gamma, beta, out);
}

// Round 3
// 401.351 us; speedup vs baseline: 1.1878x; 1.0024x over previous
//
#include <hip/hip_runtime.h>

// Fused 1x1-conv GEMM + GroupNorm + HardTanh, MI355X (gfx950).
// Round 3: single GEMM pass. Pass 1 computes y = W.x via MFMA, reduces group
// stats AND stores y as f16 to ws. Pass 2 is a pure streaming normalize+clamp
// (no recompute). k0 transpose unchanged from round 2 (passed, <=2-way LDS
// aliasing). ws budget: xT 51.4MB + wf 0.26MB + stats/ss + y 102.8MB ~ 155MB
// (measured ws ~ 822MB from harness poison fill).

#define HW    3136
#define CIN   256
#define COUT  512
#define BATCH 32
#define NG    32
#define CPG   16
#define EPS   1e-5f

typedef _Float16 f16x8 __attribute__((ext_vector_type(8)));
typedef float    f32x4 __attribute__((ext_vector_type(4)));
typedef unsigned int u32;

// async global->LDS DMA, 16B per lane; LDS dest = wave-uniform base + lane*16
__device__ __forceinline__ void gload16(const void* g, void* l) {
  __builtin_amdgcn_global_load_lds(
      (const u32 __attribute__((address_space(1)))*)g,
      (u32 __attribute__((address_space(3)))*)l, 16, 0, 0);
}

// ---------------------------------------------------------------------------
// K0: x [B][CIN][HW] f32 -> xT [B][HW][CIN] f16. 64x64 tile via fp32 LDS,
// row stride 65 dwords => <=2-way bank aliasing both phases (free per m136).
// Also converts w->f16 and zeroes the stats accumulator.
// ---------------------------------------------------------------------------
__global__ __launch_bounds__(256) void k0_transpose(
    const float* __restrict__ x, const float* __restrict__ w,
    _Float16* __restrict__ xT, _Float16* __restrict__ wf,
    float* __restrict__ stats)
{
  __shared__ float T[64 * 65];
  const int bid = blockIdx.x;
  const int t   = threadIdx.x;
  const int b   = bid / 196;       // 49 s-tiles * 4 c-tiles
  const int r   = bid % 196;
  const int st  = r >> 2;
  const int ct  = r & 3;
  const int s0  = st * 64, c0 = ct * 64;

  const float* xb = x + ((size_t)b * CIN + c0) * HW + s0;
#pragma unroll
  for (int rr = 0; rr < 4; ++rr) {
    const int c_loc = (t >> 4) + rr * 16;
    const int s4    = (t & 15) * 4;
    const float4 v  = *(const float4*)(xb + (size_t)c_loc * HW + s4);
    T[(s4 + 0) * 65 + c_loc] = v.x;
    T[(s4 + 1) * 65 + c_loc] = v.y;
    T[(s4 + 2) * 65 + c_loc] = v.z;
    T[(s4 + 3) * 65 + c_loc] = v.w;
  }
  __syncthreads();
#pragma unroll
  for (int p = 0; p < 2; ++p) {
    const int s_loc = p * 32 + (t >> 3);
    const int cg    = (t & 7) * 8;
    f16x8 o;
#pragma unroll
    for (int j = 0; j < 8; ++j) o[j] = (_Float16)T[s_loc * 65 + cg + j];
    *(f16x8*)(xT + ((size_t)b * HW + s0 + s_loc) * CIN + c0 + cg) = o;
  }
  if (bid < (COUT * CIN) / 256) wf[bid * 256 + t] = (_Float16)w[bid * 256 + t];
  if (bid < 8)                  stats[bid * 256 + t] = 0.f;
}

// ---------------------------------------------------------------------------
// K1: GEMM C[128co x 128s]/block, BK=64, 4 waves (2x2), 4x4 16x16x32 f16 MFMA
// tiles/wave. global_load_lds staging with global-side XOR chunk permutation
// (LDS image carries the swizzle -> conflict-free ds_read_b128).
// Epilogue: (a) per-group sum/sumsq wave-reduce + device atomics (group = one
// 16-row m-tile); (b) y stored as f16 in [B][COUT][HW]. Edge tile nt==24
// overlaps s in [3008,3136): y stores are bit-identical recompute
// (idempotent); stats predicated to s>=3072 to avoid double counting.
// ---------------------------------------------------------------------------
__global__ __launch_bounds__(256) void k_gemm(
    const _Float16* __restrict__ xT, const _Float16* __restrict__ wf,
    float* __restrict__ stats, _Float16* __restrict__ y)
{
  __shared__ __align__(16) _Float16 As[128 * 64];
  __shared__ __align__(16) _Float16 Bs[128 * 64];

  // XCD swizzle: 3200 blocks = 8 XCDs x 400 slots; mt fastest within an XCD
  // so the 4 mt-siblings sharing a B-tile hit the same XCD's L2.
  const int bid  = blockIdx.x;
  const int tile = (bid & 7) * 400 + (bid >> 3);
  const int mt   = tile & 3;
  const int q2   = tile >> 2;
  const int nt   = q2 % 25;
  const int b    = q2 / 25;
  const int s0   = (nt == 24) ? (HW - 128) : nt * 128;

  const int t    = threadIdx.x;
  const int lane = t & 63;
  const int wid  = t >> 6;
  const int wy   = wid >> 1, wx = wid & 1;
  const int lr   = lane >> 3;          // LDS row-within-8 this lane fills
  const int ccg  = (lane & 7) ^ lr;    // global-side chunk permutation

  f32x4 acc[4][4] = {};
  const _Float16* xb = xT + (size_t)b * HW * CIN;

  for (int kt = 0; kt < 4; ++kt) {
    __syncthreads();
    const int ko = kt * 64;
#pragma unroll
    for (int u = 0; u < 4; ++u) {
      const int rowb = (wid * 4 + u) * 8 + lr;
      gload16(wf + (size_t)(mt * 128 + rowb) * CIN + ko + ccg * 8,
              As + (wid * 4 + u) * 512);
      gload16(xb + (size_t)(s0 + rowb) * CIN + ko + ccg * 8,
              Bs + (wid * 4 + u) * 512);
    }
    __syncthreads();
#pragma unroll
    for (int ks = 0; ks < 2; ++ks) {
      const int c = ks * 4 + (lane >> 4);
      f16x8 af[4], bfr[4];
#pragma unroll
      for (int mi = 0; mi < 4; ++mi) {
        const int m = wy * 64 + mi * 16 + (lane & 15);
        af[mi] = *(const f16x8*)(As + m * 64 + ((c ^ (m & 7)) * 8));
      }
#pragma unroll
      for (int ni = 0; ni < 4; ++ni) {
        const int n = wx * 64 + ni * 16 + (lane & 15);
        bfr[ni] = *(const f16x8*)(Bs + n * 64 + ((c ^ (n & 7)) * 8));
      }
#pragma unroll
      for (int mi = 0; mi < 4; ++mi)
#pragma unroll
        for (int ni = 0; ni < 4; ++ni)
          acc[mi][ni] = __builtin_amdgcn_mfma_f32_16x16x32_f16(
              af[mi], bfr[ni], acc[mi][ni], 0, 0, 0);
    }
  }

  // ---- epilogue: stats + y f16 store ----
  const int slo  = (nt == 24) ? 3072 : 0;   // stats: skip cols already counted
  const int colb = s0 + wx * 64 + (lane & 15);
#pragma unroll
  for (int mi = 0; mi < 4; ++mi) {
    float s1 = 0.f, s2 = 0.f;
#pragma unroll
    for (int ni = 0; ni < 4; ++ni) {
      if (colb + ni * 16 >= slo) {
#pragma unroll
        for (int rr = 0; rr < 4; ++rr) {
          const float v = acc[mi][ni][rr];
          s1 += v; s2 += v * v;
        }
      }
    }
#pragma unroll
    for (int off = 32; off > 0; off >>= 1) {
      s1 += __shfl_down(s1, off, 64);
      s2 += __shfl_down(s2, off, 64);
    }
    if (lane == 0) {
      const int g = mt * 8 + wy * 4 + mi;
      atomicAdd(&stats[(b * NG + g) * 2 + 0], s1);
      atomicAdd(&stats[(b * NG + g) * 2 + 1], s2);
    }
    // y store: 4 rows x 4 col-tiles of f16 scalars; L2 merges the 32B
    // segments into full lines (sibling ni/quad iterations dirty the rest).
    const int row0 = mt * 128 + wy * 64 + mi * 16 + ((lane >> 4) << 2);
#pragma unroll
    for (int rr = 0; rr < 4; ++rr) {
      _Float16* yrow = y + ((size_t)b * COUT + row0 + rr) * HW + colb;
#pragma unroll
      for (int ni = 0; ni < 4; ++ni)
        yrow[ni * 16] = (_Float16)acc[mi][ni][rr];
    }
  }
}

// ---------------------------------------------------------------------------
// K2: per-(b,co) scale/shift: sc = rsig*gamma[co], sh = beta[co] - mean*sc
// ---------------------------------------------------------------------------
__global__ __launch_bounds__(256) void k_finalize(
    const float* __restrict__ stats, const float* __restrict__ gamma,
    const float* __restrict__ beta, float* __restrict__ ss)
{
  const int i = blockIdx.x * 256 + threadIdx.x;   // b*COUT + co
  if (i < BATCH * COUT) {
    const int b  = i >> 9;
    const int co = i & (COUT - 1);
    const int g  = co >> 4;
    const float cnt  = (float)(CPG * HW);
    const float s1   = stats[(b * NG + g) * 2 + 0];
    const float s2   = stats[(b * NG + g) * 2 + 1];
    const float mean = s1 / cnt;
    const float var  = s2 / cnt - mean * mean;
    const float rsig = rsqrtf(var + EPS);
    const float sc   = rsig * gamma[co];
    ss[i * 2 + 0] = sc;
    ss[i * 2 + 1] = beta[co] - mean * sc;
  }
}

// ---------------------------------------------------------------------------
// K3: streaming normalize + HardTanh. y f16 [B][COUT][HW] -> out f32.
// 8 elems/thread: 16B read, 2x16B write, fully coalesced.
// ---------------------------------------------------------------------------
__global__ __launch_bounds__(256) void k_norm(
    const _Float16* __restrict__ y, const float* __restrict__ ss,
    float* __restrict__ out)
{
  const u32 u   = blockIdx.x * 256 + threadIdx.x;  // 8-elem unit
  const u32 row = u / (HW / 8);                    // b*COUT + co
  const u32 sp  = (u - row * (HW / 8)) * 8;
  const float sc = ss[row * 2 + 0];
  const float sh = ss[row * 2 + 1];
  const f16x8 v = *(const f16x8*)(y + (size_t)row * HW + sp);
  float4 o0, o1;
  o0.x = fminf(fmaxf((float)v[0] * sc + sh, -2.0f), 2.0f);
  o0.y = fminf(fmaxf((float)v[1] * sc + sh, -2.0f), 2.0f);
  o0.z = fminf(fmaxf((float)v[2] * sc + sh, -2.0f), 2.0f);
  o0.w = fminf(fmaxf((float)v[3] * sc + sh, -2.0f), 2.0f);
  o1.x = fminf(fmaxf((float)v[4] * sc + sh, -2.0f), 2.0f);
  o1.y = fminf(fmaxf((float)v[5] * sc + sh, -2.0f), 2.0f);
  o1.z = fminf(fmaxf((float)v[6] * sc + sh, -2.0f), 2.0f);
  o1.w = fminf(fmaxf((float)v[7] * sc + sh, -2.0f), 2.0f);
  float* op = out + (size_t)row * HW + sp;
  *(float4*)(op)     = o0;
  *(float4*)(op + 4) = o1;
}

extern "C" void kernel_launch(void* const* d_in, const int* in_sizes, int n_in,
                              void* d_out, int out_size, void* d_ws, size_t ws_size,
                              hipStream_t stream)
{
  const float* x     = (const float*)d_in[0];
  const float* w     = (const float*)d_in[1];
  const float* gamma = (const float*)d_in[2];
  const float* beta  = (const float*)d_in[3];
  float* out = (float*)d_out;

  const size_t xT_bytes = (size_t)BATCH * HW * CIN * 2;   // 51,380,224
  const size_t wf_bytes = (size_t)COUT * CIN * 2;         //    262,144
  const size_t st_bytes = 8192;                           // 1024 pairs f32
  const size_t ss_bytes = (size_t)BATCH * COUT * 2 * 4;   //    131,072
  const size_t y_bytes  = (size_t)BATCH * COUT * HW * 2;  // 102,760,448

  char* ws = (char*)d_ws;
  _Float16* xT = (_Float16*)ws;
  _Float16* wf = (_Float16*)(ws + xT_bytes);
  float* stats = (float*)(ws + xT_bytes + wf_bytes);
  float* ss    = (float*)(ws + xT_bytes + wf_bytes + st_bytes);
  _Float16* y  = (_Float16*)(ws + xT_bytes + wf_bytes + st_bytes + ss_bytes);

  if (ws_size < xT_bytes + wf_bytes + st_bytes + ss_bytes + y_bytes) return;

  k0_transpose<<<dim3(BATCH * 196), dim3(256), 0, stream>>>(x, w, xT, wf, stats);
  k_gemm<<<dim3(BATCH * 100), dim3(256), 0, stream>>>(xT, wf, stats, y);
  k_finalize<<<dim3(BATCH * COUT / 256), dim3(256), 0, stream>>>(stats, gamma, beta, ss);
  k_norm<<<dim3(BATCH * COUT * HW / 8 / 256), dim3(256), 0, stream>>>(y, ss, out);
}